// Round 7
// baseline (203.284 us; speedup 1.0000x reference)
//
#include <hip/hip_runtime.h>

// Problem constants (fixed by setup_inputs)
constexpr int B = 4;
constexpr int C = 64;    // input channels
constexpr int O = 64;    // output channels (main conv)
constexpr int OOFF = 18; // offset channels = 2*3*3
constexpr int H = 192;
constexpr int W = 192;

typedef __attribute__((ext_vector_type(8))) _Float16 half8; // 8 f16 = 4 VGPR
typedef __attribute__((ext_vector_type(2))) _Float16 h16x2; // v_pk_fma_f16 pair
typedef __attribute__((ext_vector_type(4))) float float4v;  // MFMA acc

__device__ inline ushort f2h(float f) { // RNE f32 -> f16
  return __builtin_bit_cast(ushort, (_Float16)f);
}
__device__ inline uint pk2h(float lo, float hi) { // pack 2 f16 (RNE)
  h16x2 v;
  v.x = (_Float16)lo;
  v.y = (_Float16)hi;
  return __builtin_bit_cast(uint, v);
}

// -------------------------------------------------------------------------
// Kernel PRE (fused): blocks [0,9216): transpose x fp32 NCHW -> xtf f16
// channels-last. [9216,9360): w_conv -> wBf (PERMUTED n-map oc = nt+4*col).
// [9360,9432): w_off -> wOf (plain n-map, N padded 18->32). All f16.
// -------------------------------------------------------------------------
__global__ __launch_bounds__(256) void k_pre(const float* __restrict__ x,
                                             ushort* __restrict__ xtf,
                                             const float* __restrict__ w_conv,
                                             ushort* __restrict__ wBf,
                                             const float* __restrict__ w_off,
                                             ushort* __restrict__ wOf) {
  __shared__ float tile[64][17];
  const int bid = blockIdx.x;
  const int tid = threadIdx.x;
  if (bid < 9216) { // transpose
    const int w0 = (bid % 12) * 16;
    const int h = (bid / 12) % 192;
    const int b = bid / 2304;
    const int wl = tid & 15;
    const int c0 = tid >> 4;
#pragma unroll
    for (int r = 0; r < 4; ++r) {
      const int c = c0 + r * 16;
      tile[c][wl] = x[(((size_t)b * C + c) * H + h) * W + w0 + wl];
    }
    __syncthreads();
    const int c = tid & 63;
    const int qq = tid >> 6;
#pragma unroll
    for (int r = 0; r < 4; ++r) {
      const int wq = qq + r * 4;
      xtf[(((size_t)b * H + h) * W + w0 + wq) * C + c] = f2h(tile[c][wq]);
    }
  } else if (bid < 9360) { // wBf: 36864 entries
    const int i = (bid - 9216) * 256 + tid;
    const int j = i & 7;
    const int lane = (i >> 3) & 63;
    const int nt = (i >> 9) & 3;
    const int kstep = (i >> 11) & 1;
    const int kk = i >> 12;
    const int n = nt + 4 * (lane & 15); // permuted
    const int c = kstep * 32 + ((lane >> 4) & 3) * 8 + j;
    wBf[i] = f2h(w_conv[((size_t)n * C + c) * 9 + kk]);
  } else { // wOf: 18432 entries
    const int i = (bid - 9360) * 256 + tid;
    const int j = i & 7;
    const int lane = (i >> 3) & 63;
    const int nt = (i >> 9) & 1;
    const int ks = (i >> 10) & 1;
    const int kk = i >> 11;
    const int n = nt * 16 + (lane & 15);
    const int c = ks * 32 + ((lane >> 4) & 3) * 8 + j;
    wOf[i] = (n < OOFF) ? f2h(w_off[((size_t)n * C + c) * 9 + kk]) : (ushort)0;
  }
}

// -------------------------------------------------------------------------
// Kernel FUSED: offset-conv + deformable conv, BARRIER-FREE, fp16 MFMA.
// 8x8 px tile, 256 threads = 4 waves; all LDS exchange intra-wave.
// Phase 1: per-wave 16px x 32oc(18) x K576 f16 MFMA GEMM -> offsets in LDS.
// Phase 2: 2-AHEAD pipelined bilinear gather; blend = packed v_pk_fma_f16
// (no unpack/pack); per-wave sA slab -> 72 MFMA; epilogue -> f16 CL yt.
// grid: 2304 blocks with XCD swizzle.
// -------------------------------------------------------------------------
__global__ __launch_bounds__(256) void k_fused(
    const ushort* __restrict__ xtf, const ushort* __restrict__ wOf,
    const float* __restrict__ b_off, const ushort* __restrict__ wBf,
    const float* __restrict__ b_conv, ushort* __restrict__ yt) {
  __shared__ ushort sA[4][2][64][8];                // [wave][ks][lane][j] = 8 KB
  __shared__ __align__(16) float offBuf[4][16][20]; // [wave][pl][oc(18,pad20)]

  const int bid = blockIdx.x;
  const int xcd = bid & 7;
  const int s = bid >> 3; // 0..287
  const int b = xcd >> 1;
  const int half = xcd & 1;
  const int th = half * 12 + s / 24; // 0..23
  const int tw = s % 24;             // 0..23
  const int h0 = th * 8, w0 = tw * 8;

  const int tid = threadIdx.x;
  const int wave = tid >> 6, lane = tid & 63;
  const int col = lane & 15, quad = lane >> 4;
  const int p = tid >> 2, qtr = tid & 3;
  const int pl = p & 15; // wave-local pixel
  const int prow = p >> 3, pcol = p & 7;
  const int h = h0 + prow, w = w0 + pcol;
  const int ks_w = qtr >> 1;    // LDS ks plane for gather writes
  const int q2 = (qtr & 1) * 2; // first quad row

  // ===================== Phase 1: offset conv (per wave) =====================
  {
    float4v oacc[2];
#pragma unroll
    for (int nt = 0; nt < 2; ++nt) oacc[nt] = (float4v){0.f, 0.f, 0.f, 0.f};

    half8 obfr[2][2][2]; // [pb][ks][nt]
    half8 oafr[2][2];    // [pb][ks]

    auto oload = [&](int kk, int pb) {
      const int ky = kk / 3, kx = kk % 3;
      const int hh = h0 + 2 * wave + (col >> 3) + ky - 1;
      const int ww = w0 + (col & 7) + kx - 1;
      const bool ok = ((unsigned)hh < (unsigned)H) && ((unsigned)ww < (unsigned)W);
      const int hhc = min(max(hh, 0), H - 1);
      const int wwc = min(max(ww, 0), W - 1);
      const ushort* pa = xtf + (((size_t)b * H + hhc) * W + wwc) * C + quad * 8;
#pragma unroll
      for (int ks = 0; ks < 2; ++ks) {
        half8 v = (half8)0;
        if (ok) v = *(const half8*)(pa + ks * 32);
        oafr[pb][ks] = v;
#pragma unroll
        for (int nt = 0; nt < 2; ++nt)
          obfr[pb][ks][nt] = *(const half8*)&wOf[((((size_t)kk * 2 + ks) * 2 + nt) * 64 + lane) * 8];
      }
    };

    oload(0, 0);
#pragma unroll
    for (int kk = 0; kk < 9; ++kk) {
      const int pb = kk & 1;
      if (kk < 8) oload(kk + 1, pb ^ 1);
#pragma unroll
      for (int ks = 0; ks < 2; ++ks)
#pragma unroll
        for (int nt = 0; nt < 2; ++nt)
          oacc[nt] = __builtin_amdgcn_mfma_f32_16x16x32_f16(oafr[pb][ks], obfr[pb][ks][nt],
                                                            oacc[nt], 0, 0, 0);
    }

    // distribute offsets: D[m=quad*4+r][n=nt*16+col] -> offBuf[wave][m][oc]
#pragma unroll
    for (int nt = 0; nt < 2; ++nt) {
      const int oc = nt * 16 + col;
      if (oc < OOFF) {
        const float bias = b_off[oc];
#pragma unroll
        for (int r = 0; r < 4; ++r)
          offBuf[wave][quad * 4 + r][oc] = oacc[nt][r] + bias;
      }
    }
  } // intra-wave LDS exchange: no barrier needed (same-wave ds ordering)

  // ===================== Phase 2: deformable conv =====================
  // hoist all 9 offset pairs into registers (one contiguous LDS read burst)
  float2 offv[9];
#pragma unroll
  for (int kk = 0; kk < 9; ++kk) offv[kk] = *(const float2*)&offBuf[wave][pl][2 * kk];

  const ushort* xb = xtf + (size_t)b * H * W * C + qtr * 16;

  uint4 G[3][8]; // 3-buffer (2-ahead) gather registers (4 corners x 2 uint4)
  float4 aw[3];  // bilinear weights per buffer

  auto issue = [&](int kk, int buf) {
    const float dy = offv[kk].x, dx = offv[kk].y;
    const int ky = kk / 3, kx = kk % 3;
    const float pyf = dy + (float)(ky + h - 1);
    const float pxf = dx + (float)(kx + w - 1);
    const float fy0 = floorf(pyf), fx0 = floorf(pxf);
    const float wy = pyf - fy0, wx = pxf - fx0;
    const int iy0 = (int)fy0, ix0 = (int)fx0;
    const int iy1 = iy0 + 1, ix1 = ix0 + 1;
    const bool vy0 = (unsigned)iy0 < (unsigned)H;
    const bool vy1 = (unsigned)iy1 < (unsigned)H;
    const bool vx0 = (unsigned)ix0 < (unsigned)W;
    const bool vx1 = (unsigned)ix1 < (unsigned)W;
    aw[buf].x = (vy0 && vx0) ? (1.f - wy) * (1.f - wx) : 0.f;
    aw[buf].y = (vy0 && vx1) ? (1.f - wy) * wx : 0.f;
    aw[buf].z = (vy1 && vx0) ? wy * (1.f - wx) : 0.f;
    aw[buf].w = (vy1 && vx1) ? wy * wx : 0.f;
    const int cy0 = min(max(iy0, 0), H - 1), cy1 = min(max(iy1, 0), H - 1);
    const int cx0 = min(max(ix0, 0), W - 1), cx1 = min(max(ix1, 0), W - 1);
    const uint4* p00 = (const uint4*)(xb + ((size_t)cy0 * W + cx0) * C);
    const uint4* p01 = (const uint4*)(xb + ((size_t)cy0 * W + cx1) * C);
    const uint4* p10 = (const uint4*)(xb + ((size_t)cy1 * W + cx0) * C);
    const uint4* p11 = (const uint4*)(xb + ((size_t)cy1 * W + cx1) * C);
    G[buf][0] = p00[0]; G[buf][1] = p00[1];
    G[buf][2] = p01[0]; G[buf][3] = p01[1];
    G[buf][4] = p10[0]; G[buf][5] = p10[1];
    G[buf][6] = p11[0]; G[buf][7] = p11[1];
  };

  float4v acc[4];
#pragma unroll
  for (int nt = 0; nt < 4; ++nt) acc[nt] = (float4v){0.f, 0.f, 0.f, 0.f};

  issue(0, 0);
  issue(1, 1);
#pragma unroll
  for (int kk = 0; kk < 9; ++kk) {
    const int buf = kk % 3;
    if (kk < 7) issue(kk + 2, (kk + 2) % 3); // 2-ahead: next-next gather in flight

    // packed f16 blend: 4 v_pk_fma_f16 per 2 channels, no unpack/pack
    const _Float16 w00 = (_Float16)aw[buf].x, w01 = (_Float16)aw[buf].y;
    const _Float16 w10 = (_Float16)aw[buf].z, w11 = (_Float16)aw[buf].w;
    const h16x2 a00 = {w00, w00}, a01 = {w01, w01}, a10 = {w10, w10}, a11 = {w11, w11};
    uint pk[8];
#pragma unroll
    for (int i = 0; i < 8; ++i) {
      const h16x2 v00 = __builtin_bit_cast(h16x2, ((const uint*)&G[buf][0])[i]);
      const h16x2 v01 = __builtin_bit_cast(h16x2, ((const uint*)&G[buf][2])[i]);
      const h16x2 v10 = __builtin_bit_cast(h16x2, ((const uint*)&G[buf][4])[i]);
      const h16x2 v11 = __builtin_bit_cast(h16x2, ((const uint*)&G[buf][6])[i]);
      const h16x2 sv = v00 * a00 + v01 * a01 + v10 * a10 + v11 * a11;
      pk[i] = __builtin_bit_cast(uint, sv);
    }
    // intra-wave exchange (same-wave ds_write -> ds_read ordering)
    *(uint4*)&sA[wave][ks_w][pl | (q2 << 4)][0] = *(const uint4*)&pk[0];
    *(uint4*)&sA[wave][ks_w][pl | ((q2 + 1) << 4)][0] = *(const uint4*)&pk[4];

#pragma unroll
    for (int ks = 0; ks < 2; ++ks) {
      const half8 a = *(const half8*)&sA[wave][ks][lane][0];
#pragma unroll
      for (int nt = 0; nt < 4; ++nt) {
        const half8 bb = *(const half8*)&wBf[((((size_t)kk * 2 + ks) * 4 + nt) * 64 + lane) * 8];
        acc[nt] = __builtin_amdgcn_mfma_f32_16x16x32_f16(a, bb, acc[nt], 0, 0, 0);
      }
    }
  }

  // epilogue: yt[b][h][w][c] f16, oc = nt + 4*(lane&15) (permuted)
  float bias[4];
#pragma unroll
  for (int nt = 0; nt < 4; ++nt) bias[nt] = b_conv[4 * col + nt];
#pragma unroll
  for (int r = 0; r < 4; ++r) {
    const int pp = wave * 16 + quad * 4 + r; // pixel index in 8x8 tile
    const int hrow = h0 + (pp >> 3), wcol = w0 + (pp & 7);
    uint2 u;
    u.x = pk2h(acc[0][r] + bias[0], acc[1][r] + bias[1]);
    u.y = pk2h(acc[2][r] + bias[2], acc[3][r] + bias[3]);
    *(uint2*)&yt[((size_t)(b * H + hrow) * W + wcol) * C + 4 * col] = u;
  }
}

// -------------------------------------------------------------------------
// Kernel 4: main 3x3 conv via f16 MFMA, LDS-free, 4 rows/wave (32 MFMA per
// 16 loads), 1-ahead pipelined frags. Block = 16 rows; grid (12,12,4)=576.
// -------------------------------------------------------------------------
__global__ __launch_bounds__(256) void k_conv_main_mfma(
    const ushort* __restrict__ yt, const ushort* __restrict__ wBf,
    const float* __restrict__ b_conv, float* __restrict__ out) {
  const int w0 = blockIdx.x * 16;
  const int b = blockIdx.z;
  const int tid = threadIdx.x;
  const int wave = tid >> 6, lane = tid & 63;
  const int col = lane & 15, quad = lane >> 4;
  const int h0 = blockIdx.y * 16 + wave * 4;

  float4v acc[4][4];
#pragma unroll
  for (int mt = 0; mt < 4; ++mt)
#pragma unroll
    for (int nt = 0; nt < 4; ++nt) acc[mt][nt] = (float4v){0.f, 0.f, 0.f, 0.f};

  half8 bfr[2][2][4]; // [pb][ks][nt]
  half8 afr[2][4][2]; // [pb][mt][ks]

  auto load = [&](int kk, int pb) {
    const int ky = kk / 3, kx = kk % 3;
    const int ww = w0 + col + kx - 1;
    const bool wok = (unsigned)ww < (unsigned)W;
    const int wwc = min(max(ww, 0), W - 1);
#pragma unroll
    for (int ks = 0; ks < 2; ++ks)
#pragma unroll
      for (int nt = 0; nt < 4; ++nt)
        bfr[pb][ks][nt] = *(const half8*)&wBf[((((size_t)kk * 2 + ks) * 4 + nt) * 64 + lane) * 8];
#pragma unroll
    for (int mt = 0; mt < 4; ++mt) {
      const int hh = h0 + mt + ky - 1;
      const bool ok = wok && ((unsigned)hh < (unsigned)H);
      const int hhc = min(max(hh, 0), H - 1);
      const ushort* pa = yt + (((size_t)b * H + hhc) * W + wwc) * C + quad * 8;
#pragma unroll
      for (int ks = 0; ks < 2; ++ks) {
        half8 v = (half8)0;
        if (ok) v = *(const half8*)(pa + ks * 32);
        afr[pb][mt][ks] = v;
      }
    }
  };

  load(0, 0);
#pragma unroll
  for (int kk = 0; kk < 9; ++kk) {
    const int pb = kk & 1;
    if (kk < 8) load(kk + 1, pb ^ 1);
#pragma unroll
    for (int ks = 0; ks < 2; ++ks)
#pragma unroll
      for (int mt = 0; mt < 4; ++mt)
#pragma unroll
        for (int nt = 0; nt < 4; ++nt)
          acc[mt][nt] = __builtin_amdgcn_mfma_f32_16x16x32_f16(afr[pb][mt][ks], bfr[pb][ks][nt],
                                                               acc[mt][nt], 0, 0, 0);
  }

  float bias[4];
#pragma unroll
  for (int nt = 0; nt < 4; ++nt) bias[nt] = b_conv[4 * col + nt];
#pragma unroll
  for (int mt = 0; mt < 4; ++mt) {
    const int h = h0 + mt;
#pragma unroll
    for (int nt = 0; nt < 4; ++nt) {
      const int oc = 4 * col + nt; // permuted C/D col -> oc
      float4 v;
      v.x = acc[mt][nt][0] + bias[nt];
      v.y = acc[mt][nt][1] + bias[nt];
      v.z = acc[mt][nt][2] + bias[nt];
      v.w = acc[mt][nt][3] + bias[nt];
      *(float4*)&out[(((size_t)b * O + oc) * H + h) * W + w0 + quad * 4] = v;
    }
  }
}

// -------------------------------------------------------------------------
extern "C" void kernel_launch(void* const* d_in, const int* in_sizes, int n_in,
                              void* d_out, int out_size, void* d_ws, size_t ws_size,
                              hipStream_t stream) {
  const float* x = (const float*)d_in[0];
  const float* w_off = (const float*)d_in[1];
  const float* b_off = (const float*)d_in[2];
  const float* w_conv = (const float*)d_in[3];
  const float* b_conv = (const float*)d_in[4];
  float* out = (float*)d_out;

  ushort* xtf = (ushort*)d_ws;              // B*H*W*C f16
  ushort* yt = xtf + (size_t)B * H * W * C; // B*H*W*C f16
  ushort* wBf = yt + (size_t)B * H * W * C; // 36864 f16
  ushort* wOf = wBf + 36864;                // 18432 f16

  const dim3 blk(256);
  k_pre<<<dim3(9432), blk, 0, stream>>>(x, xtf, w_conv, wBf, w_off, wOf);
  k_fused<<<dim3(2304), blk, 0, stream>>>(xtf, wOf, b_off, wBf, b_conv, yt);
  k_conv_main_mfma<<<dim3(W / 16, H / 16, B), blk, 0, stream>>>(yt, wBf, b_conv, out);
}